// Round 5
// baseline (1499.869 us; speedup 1.0000x reference)
//
#include <hip/hip_runtime.h>
#include <stdint.h>

// ---------------------------------------------------------------------------
// PointNet-style graph autoencoder, MI355X (gfx950).
//
// R5: (1) Gs stored bf16 (halves the random per-edge gather bytes),
//     (2) software-pipelined K-loops (register prefetch across the barrier)
//         in both edge and node GEMMs,
//     (3) parallel 3-kernel prefix scan for the counting sort,
//     (4) fused finalize_h + init_agg.
// Edges counting-sorted by dst once; one atomicMax per (run, col).
// ---------------------------------------------------------------------------

using bf16x8 = __attribute__((ext_vector_type(8))) short;
using f32x4  = __attribute__((ext_vector_type(4))) float;

#define AB_STRIDE 40      // shorts per staged row (32 k + 8 pad) -> 16B aligned
#define ZSTRIDE   68      // shorts per Z column (64 rows + 4 pad)

__device__ __forceinline__ float b2f(uint32_t v16) {          // bf16 bits -> f32
    return __uint_as_float(v16 << 16);
}
__device__ __forceinline__ float b2f_hi(uint32_t w) {         // high bf16 of word
    return __uint_as_float(w & 0xffff0000u);
}
__device__ __forceinline__ uint16_t f2b(float f) {            // f32 -> bf16 (RNE)
    uint32_t u = __float_as_uint(f);
    u += 0x7fffu + ((u >> 16) & 1u);
    return (uint16_t)(u >> 16);
}
#if __has_builtin(__builtin_amdgcn_cvt_pk_bf16_f32)
__device__ __forceinline__ uint32_t pack2bf(float lo, float hi) {
    auto r = __builtin_amdgcn_cvt_pk_bf16_f32(lo, hi);   // RNE
    uint32_t u; __builtin_memcpy(&u, &r, 4); return u;
}
#else
__device__ __forceinline__ uint32_t pack2bf(float lo, float hi) {
    return (uint32_t)f2b(lo) | ((uint32_t)f2b(hi) << 16);
}
#endif
// monotone float<->uint mapping for atomicMax-based segment_max
__device__ __forceinline__ uint32_t encf(float f) {
    uint32_t u = __float_as_uint(f);
    return (u & 0x80000000u) ? ~u : (u | 0x80000000u);
}
__device__ __forceinline__ float decf(uint32_t k) {
    uint32_t u = (k & 0x80000000u) ? (k & 0x7fffffffu) : ~k;
    return __uint_as_float(u);
}

// ---------------------------------------------------------------------------
// Dtype detection. flags[0]=1 if float tensors are fp32 (else bf16),
// flags[1]=1 if edge_index is int64 (else int32).
// ---------------------------------------------------------------------------
__global__ void detect_fmt(const uint32_t* __restrict__ x,
                           const uint32_t* __restrict__ ei,
                           uint32_t* __restrict__ flags) {
    if (threadIdx.x == 0 && blockIdx.x == 0) {
        int plaus = 0;
        for (int i = 0; i < 64; i++) {
            uint32_t v = x[i];
            uint32_t e = (v >> 23) & 0xffu;
            if (v == 0u || (e >= 96u && e <= 150u)) plaus++;
        }
        flags[0] = (plaus >= 48) ? 1u : 0u;
        int zeros = 0;
        for (int i = 0; i < 16; i++)
            if (ei[2 * i + 1] == 0u) zeros++;
        flags[1] = (zeros == 16) ? 1u : 0u;
    }
}

// big float tensor -> canonical bf16 (4 elems/thread)
__global__ __launch_bounds__(256) void convert_big(
        const void* __restrict__ src, uint16_t* __restrict__ dst, int n,
        const uint32_t* __restrict__ flags) {
    bool isf32 = flags[0] != 0u;
    int i = (blockIdx.x * 256 + threadIdx.x) * 4;
    if (i + 3 < n) {
        if (isf32) {
            float4 v = ((const float4*)src)[i >> 2];
            uint2 o = {pack2bf(v.x, v.y), pack2bf(v.z, v.w)};
            ((uint2*)dst)[i >> 2] = o;
        } else {
            ((uint2*)dst)[i >> 2] = ((const uint2*)src)[i >> 2];
        }
    } else {
        for (int j = i; j < n; j++)
            dst[j] = isf32 ? f2b(((const float*)src)[j]) : ((const uint16_t*)src)[j];
    }
}

struct ConvArgs {
    const void* src[13];
    uint32_t dstOff[13];
    uint32_t n[13];
};

// batched small float tensors -> canonical bf16 arena
__global__ __launch_bounds__(256) void convert_small(
        ConvArgs a, uint16_t* __restrict__ dstBase, const uint32_t* __restrict__ flags) {
    bool isf32 = flags[0] != 0u;
    int t = blockIdx.y;
    int i = blockIdx.x * 256 + threadIdx.x;
    if (i >= (int)a.n[t]) return;
    uint16_t* d = dstBase + a.dstOff[t];
    d[i] = isf32 ? f2b(((const float*)a.src[t])[i]) : ((const uint16_t*)a.src[t])[i];
}

// ---------------------------------------------------------------------------
// Counting sort of edges by dst (parallel 3-kernel scan).
// ---------------------------------------------------------------------------
__global__ __launch_bounds__(256) void zero_i32(int* p, int n) {
    int i = blockIdx.x * 256 + threadIdx.x;
    if (i < n) p[i] = 0;
}

__global__ __launch_bounds__(256) void hist_dst(
        const int* __restrict__ ei_raw, int E, int* __restrict__ hist,
        const uint32_t* __restrict__ flags) {
    bool i64 = flags[1] != 0u;
    int e = blockIdx.x * 256 + threadIdx.x;
    if (e < E) {
        int d = i64 ? ei_raw[2 * (E + e)] : ei_raw[E + e];
        atomicAdd(&hist[d], 1);
    }
}

// per-1024-chunk exclusive scan + chunk totals
__global__ __launch_bounds__(1024) void scan_partial(
        const int* __restrict__ hist, int* __restrict__ cursor,
        int* __restrict__ part, int N) {
    __shared__ int wsum[16];
    int tid = threadIdx.x, lane = tid & 63, wid = tid >> 6;
    int base = blockIdx.x * 1024;
    int v = (base + tid < N) ? hist[base + tid] : 0;
    int x = v;
#pragma unroll
    for (int s = 1; s < 64; s <<= 1) {
        int t = __shfl_up(x, s, 64);
        if (lane >= s) x += t;
    }
    if (lane == 63) wsum[wid] = x;
    __syncthreads();
    if (wid == 0 && lane < 16) {
        int w = wsum[lane];
#pragma unroll
        for (int s = 1; s < 16; s <<= 1) {
            int t = __shfl_up(w, s, 64);
            if (lane >= s) w += t;
        }
        wsum[lane] = w;
    }
    __syncthreads();
    int wbase = (wid > 0) ? wsum[wid - 1] : 0;
    if (base + tid < N) cursor[base + tid] = x - v + wbase;
    if (tid == 0) part[blockIdx.x] = wsum[15];
}

// exclusive scan of chunk totals (B <= 1024)
__global__ __launch_bounds__(1024) void scan_carry(
        const int* __restrict__ part, int* __restrict__ carry, int B) {
    __shared__ int wsum[16];
    int tid = threadIdx.x, lane = tid & 63, wid = tid >> 6;
    int v = (tid < B) ? part[tid] : 0;
    int x = v;
#pragma unroll
    for (int s = 1; s < 64; s <<= 1) {
        int t = __shfl_up(x, s, 64);
        if (lane >= s) x += t;
    }
    if (lane == 63) wsum[wid] = x;
    __syncthreads();
    if (wid == 0 && lane < 16) {
        int w = wsum[lane];
#pragma unroll
        for (int s = 1; s < 16; s <<= 1) {
            int t = __shfl_up(w, s, 64);
            if (lane >= s) w += t;
        }
        wsum[lane] = w;
    }
    __syncthreads();
    int wbase = (wid > 0) ? wsum[wid - 1] : 0;
    if (tid < B) carry[tid] = x - v + wbase;
}

__global__ __launch_bounds__(1024) void scan_add(
        int* __restrict__ cursor, const int* __restrict__ carry, int N) {
    int i = blockIdx.x * 1024 + threadIdx.x;
    if (i < N) cursor[i] += carry[blockIdx.x];
}

__global__ __launch_bounds__(256) void scatter_edges(
        const int* __restrict__ ei_raw, int E, int* __restrict__ cursor,
        int* __restrict__ esrc, int* __restrict__ edst,
        const uint32_t* __restrict__ flags) {
    bool i64 = flags[1] != 0u;
    int e = blockIdx.x * 256 + threadIdx.x;
    if (e < E) {
        int s = i64 ? ei_raw[2 * e] : ei_raw[e];
        int d = i64 ? ei_raw[2 * (E + e)] : ei_raw[E + e];
        int p = atomicAdd(&cursor[d], 1);
        esrc[p] = s;
        edst[p] = d;
    }
}

// ---------------------------------------------------------------------------
// Transpose+chunk-tile the 6 [256x256] B-matrices into WT (32-k chunks):
//   WT[w][ (k>>5)*8192 + n*32 + (k&31) ] = W[k*256 + n]
// ---------------------------------------------------------------------------
__global__ __launch_bounds__(256) void transpose_w(
        const uint16_t* s0, const uint16_t* s1, const uint16_t* s2,
        const uint16_t* s3, const uint16_t* s4, const uint16_t* s5,
        uint16_t* dst) {
    const uint16_t* srcs[6] = {s0, s1, s2, s3, s4, s5};
    const uint16_t* src = srcs[blockIdx.y];
    uint16_t* d = dst + (size_t)blockIdx.y * 65536;
    int k = blockIdx.x;          // grid.x = 256
    int n = threadIdx.x;
    d[(k >> 5) * 8192 + n * 32 + (k & 31)] = src[k * 256 + n];
}

// Q[i][c] = sum_d pos[i][d] * wpos[d][c]   (wpos = wA rows 256..258)
__global__ __launch_bounds__(256) void pos_proj(
        const uint16_t* pos, const uint16_t* wpos, uint16_t* Q, int N) {
    int c = threadIdx.x;
    float w0 = b2f(wpos[c]), w1 = b2f(wpos[256 + c]), w2 = b2f(wpos[512 + c]);
    int base = blockIdx.x * 8;
#pragma unroll
    for (int n = 0; n < 8; n++) {
        int i = base + n;
        if (i >= N) break;
        float p0 = b2f(pos[i * 3 + 0]);
        float p1 = b2f(pos[i * 3 + 1]);
        float p2 = b2f(pos[i * 3 + 2]);
        Q[(size_t)i * 256 + c] = f2b(p0 * w0 + p1 * w1 + p2 * w2);
    }
}

__global__ __launch_bounds__(256) void init_agg(uint32_t* agg, int n4) {
    int i = blockIdx.x * 256 + threadIdx.x;
    if (i < n4) {
        uint4 v = {0x80000000u, 0x80000000u, 0x80000000u, 0x80000000u};  // enc(+0)
        ((uint4*)agg)[i] = v;
    }
}

// fused: h = bf16(dec(agg)); agg = enc(0) for the next layer
__global__ __launch_bounds__(256) void finalize_init(
        uint32_t* __restrict__ agg, uint16_t* __restrict__ h, int n4) {
    int i = blockIdx.x * 256 + threadIdx.x;
    if (i < n4) {
        uint4 a = ((uint4*)agg)[i];
        uint2 o = {pack2bf(decf(a.x), decf(a.y)), pack2bf(decf(a.z), decf(a.w))};
        ((uint2*)h)[i] = o;
        uint4 z = {0x80000000u, 0x80000000u, 0x80000000u, 0x80000000u};
        ((uint4*)agg)[i] = z;
    }
}

// ---------------------------------------------------------------------------
// Node GEMM (BK=32, software-pipelined): C[M,256] = A @ W (+bias) (+Q) (...)
// Tile: 64 rows x 256 cols, 256 threads / 4 waves; wave w owns cols [w*64,+64).
// MODE 0: out bf16, +bias +Q (Gs build).  MODE 1: out bf16, +bias, relu.
// MODE 2: out per-flag dtype, +bias (final decoder stage).
// ---------------------------------------------------------------------------
template <int MODE>
__global__ __launch_bounds__(256) void gemm_node(
        const uint16_t* __restrict__ A, const uint16_t* __restrict__ BT,
        const uint16_t* __restrict__ bias, const uint16_t* __restrict__ Qadd,
        void* __restrict__ out, int M, const uint32_t* __restrict__ flags) {
    __shared__ __align__(16) uint16_t Al[64 * AB_STRIDE];
    __shared__ __align__(16) uint16_t Bl[256 * AB_STRIDE];
    int tid = threadIdx.x;
    int tileM = blockIdx.x;
    int wave = tid >> 6, lane = tid & 63, lrow = lane & 15, quad = lane >> 4;
    f32x4 acc[4][4] = {};

    int row = tid >> 2, kq = (tid & 3) * 8;
    int rg = tileM * 64 + row;
    bool rok = rg < M;
    const uint16_t* abase = A + (size_t)(rok ? rg : 0) * 256 + kq;

    // prologue prefetch (kc = 0)
    uint4 av = {0, 0, 0, 0};
    if (rok) av = *(const uint4*)(abase);
    uint4 pb[4];
#pragma unroll
    for (int j = 0; j < 4; j++) pb[j] = ((const uint4*)(BT + tid * 32))[j];

    for (int kc = 0; kc < 256; kc += 32) {
        __syncthreads();                       // prior frag reads done
        *(uint4*)&Al[row * AB_STRIDE + kq] = rok ? av : uint4{0, 0, 0, 0};
#pragma unroll
        for (int j = 0; j < 4; j++) *(uint4*)&Bl[tid * AB_STRIDE + j * 8] = pb[j];
        __syncthreads();
        if (kc + 32 < 256) {                   // prefetch kc+32 (overlaps MFMA)
            if (rok) av = *(const uint4*)(abase + kc + 32);
            const uint4* p = (const uint4*)(BT + ((kc + 32) >> 5) * 8192 + tid * 32);
#pragma unroll
            for (int j = 0; j < 4; j++) pb[j] = p[j];
        }
        bf16x8 af[4], bfr[4];
#pragma unroll
        for (int r = 0; r < 4; r++)
            af[r] = *(const bf16x8*)&Al[(r * 16 + lrow) * AB_STRIDE + quad * 8];
#pragma unroll
        for (int c = 0; c < 4; c++)
            bfr[c] = *(const bf16x8*)&Bl[(wave * 64 + c * 16 + lrow) * AB_STRIDE + quad * 8];
#pragma unroll
        for (int r = 0; r < 4; r++)
#pragma unroll
            for (int c = 0; c < 4; c++)
                acc[r][c] = __builtin_amdgcn_mfma_f32_16x16x32_bf16(af[r], bfr[c], acc[r][c], 0, 0, 0);
    }

    bool of32 = false;
    if (MODE == 2) of32 = flags[0] != 0u;

#pragma unroll
    for (int c = 0; c < 4; c++) {
        int col = wave * 64 + c * 16 + lrow;
        float bv = b2f(bias[col]);
#pragma unroll
        for (int r = 0; r < 4; r++) {
#pragma unroll
            for (int i = 0; i < 4; i++) {
                int rw = tileM * 64 + r * 16 + quad * 4 + i;
                if (rw >= M) continue;
                float v = acc[r][c][i] + bv;
                if (MODE == 0) {
                    v += b2f(Qadd[(size_t)rw * 256 + col]);
                    ((uint16_t*)out)[(size_t)rw * 256 + col] = f2b(v);
                } else if (MODE == 1) {
                    v = fmaxf(v, 0.f);
                    ((uint16_t*)out)[(size_t)rw * 256 + col] = f2b(v);
                } else {
                    if (of32) ((float*)out)[(size_t)rw * 256 + col] = v;
                    else      ((uint16_t*)out)[(size_t)rw * 256 + col] = f2b(v);
                }
            }
        }
    }
}

// ---------------------------------------------------------------------------
// Edge kernel over dst-SORTED edges (BK=32, software-pipelined):
// tile = 64 edges x 256 cols. m = relu(Gs16[src] - Q[dst]) -> bf16 (Gs bf16);
// z = m @ wB + bB. Z parked col-major in LDS (overlay); run-max scan with
// ballot mask; one coalesced atomicMax per (run, col).
// ---------------------------------------------------------------------------
__global__ __launch_bounds__(256, 4) void edge_gemm_agg(
        const uint16_t* __restrict__ Gs16, const uint16_t* __restrict__ Qb,
        const uint16_t* __restrict__ BT, const uint16_t* __restrict__ bias,
        const int* __restrict__ esrc, const int* __restrict__ edst, int E,
        uint32_t* __restrict__ agg) {
    __shared__ __align__(16) uint16_t SM[256 * ZSTRIDE];     // 34816 B
    uint16_t* Al = SM;                       // 64 x AB_STRIDE
    uint16_t* Bl = SM + 64 * AB_STRIDE;      // 256 x AB_STRIDE
    uint16_t* Zl = SM;                       // overlay: col-major 256 x ZSTRIDE
    __shared__ int ssrc[64], sdst[64];
    __shared__ uint64_t smask;
    int tid = threadIdx.x;
    int ebase = blockIdx.x * 64;
    int evalid = (E - ebase < 64) ? (E - ebase) : 64;
    if (tid < 64) {
        int s = 0, d = 0;
        if (tid < evalid) {
            s = esrc[ebase + tid];
            d = edst[ebase + tid];
        }
        ssrc[tid] = s;
        sdst[tid] = d;
    }
    __syncthreads();
    int wave = tid >> 6, lane = tid & 63, lrow = lane & 15, quad = lane >> 4;
    f32x4 acc[4][4] = {};

    int row = tid >> 2, kq = (tid & 3) * 8;
    int s = ssrc[row], dd = sdst[row];
    const uint16_t* gbase = Gs16 + (size_t)s * 256 + kq;
    const uint16_t* qbase = Qb + (size_t)dd * 256 + kq;

    // prologue prefetch (kc = 0)
    uint4 ga = *(const uint4*)(gbase);
    uint4 qa = *(const uint4*)(qbase);
    uint4 pb[4];
#pragma unroll
    for (int j = 0; j < 4; j++) pb[j] = ((const uint4*)(BT + tid * 32))[j];

    for (int kc = 0; kc < 256; kc += 32) {
        // m = relu(g - q) -> packed bf16 (8 elems)
        uint32_t gw[4] = {ga.x, ga.y, ga.z, ga.w};
        uint32_t qw[4] = {qa.x, qa.y, qa.z, qa.w};
        uint32_t mw[4];
#pragma unroll
        for (int j = 0; j < 4; j++) {
            float lo = fmaxf(b2f(gw[j] & 0xffffu) - b2f(qw[j] & 0xffffu), 0.f);
            float hi = fmaxf(b2f_hi(gw[j]) - b2f_hi(qw[j]), 0.f);
            mw[j] = pack2bf(lo, hi);
        }
        __syncthreads();                       // prior frag reads done
        uint4 wv = {mw[0], mw[1], mw[2], mw[3]};
        *(uint4*)&Al[row * AB_STRIDE + kq] = wv;
#pragma unroll
        for (int j = 0; j < 4; j++) *(uint4*)&Bl[tid * AB_STRIDE + j * 8] = pb[j];
        __syncthreads();
        if (kc + 32 < 256) {                   // prefetch kc+32 (overlaps MFMA)
            ga = *(const uint4*)(gbase + kc + 32);
            qa = *(const uint4*)(qbase + kc + 32);
            const uint4* p = (const uint4*)(BT + ((kc + 32) >> 5) * 8192 + tid * 32);
#pragma unroll
            for (int j = 0; j < 4; j++) pb[j] = p[j];
        }
        bf16x8 af[4], bfr[4];
#pragma unroll
        for (int r = 0; r < 4; r++)
            af[r] = *(const bf16x8*)&Al[(r * 16 + lrow) * AB_STRIDE + quad * 8];
#pragma unroll
        for (int c = 0; c < 4; c++)
            bfr[c] = *(const bf16x8*)&Bl[(wave * 64 + c * 16 + lrow) * AB_STRIDE + quad * 8];
#pragma unroll
        for (int r = 0; r < 4; r++)
#pragma unroll
            for (int c = 0; c < 4; c++)
                acc[r][c] = __builtin_amdgcn_mfma_f32_16x16x32_bf16(af[r], bfr[c], acc[r][c], 0, 0, 0);
    }
    __syncthreads();                            // last frag reads before Z overlay

    // park z = acc + bias in LDS col-major as bf16 (RNE monotone: commutes w/ max)
    float bv[4];
#pragma unroll
    for (int c = 0; c < 4; c++) bv[c] = b2f(bias[wave * 64 + c * 16 + lrow]);
#pragma unroll
    for (int c = 0; c < 4; c++) {
        int col = wave * 64 + c * 16 + lrow;
#pragma unroll
        for (int r = 0; r < 4; r++) {
            uint2 z4 = {pack2bf(acc[r][c][0] + bv[c], acc[r][c][1] + bv[c]),
                        pack2bf(acc[r][c][2] + bv[c], acc[r][c][3] + bv[c])};
            *(uint2*)&Zl[col * ZSTRIDE + r * 16 + quad * 4] = z4;
        }
    }
    // run-boundary mask (uniform): bit r set where sdst[r] != sdst[r-1]
    if (wave == 0) {
        int d0 = sdst[lane];
        int dp = (lane > 0) ? sdst[lane - 1] : -1;
        uint64_t m = __ballot(d0 != dp);
        if (lane == 0) smask = m;
    }
    __syncthreads();

    // run-max over sorted dst, one coalesced atomic per (run, col)
    uint64_t mask = smask;
    int col = tid;
    const uint16_t* zc = &Zl[col * ZSTRIDE];
    float run = 0.f;
#pragma unroll 4
    for (int g = 0; g < 16; g++) {
        int rbase = g * 4;
        if (rbase >= evalid) break;
        uint2 z4 = *(const uint2*)&zc[rbase];
        float vv[4] = {b2f(z4.x & 0xffffu), b2f_hi(z4.x),
                       b2f(z4.y & 0xffffu), b2f_hi(z4.y)};
#pragma unroll
        for (int i = 0; i < 4; i++) {
            int r = rbase + i;
            if (r >= evalid) break;
            if (r == 0) {
                run = vv[0];
            } else if ((mask >> r) & 1ull) {
                int dp = sdst[r - 1];
                atomicMax(agg + (size_t)dp * 256 + col, encf(run));
                run = vv[i];
            } else {
                run = fmaxf(run, vv[i]);
            }
        }
    }
    if (evalid > 0)
        atomicMax(agg + (size_t)sdst[evalid - 1] * 256 + col, encf(run));
}

// ---------------------------------------------------------------------------
extern "C" void kernel_launch(void* const* d_in, const int* in_sizes, int n_in,
                              void* d_out, int out_size, void* d_ws, size_t ws_size,
                              hipStream_t stream) {
    const void* x_raw   = d_in[0];
    const void* pos_raw = d_in[1];
    const int*  ei_raw  = (const int*)d_in[2];

    int N = in_sizes[0] / 256;     // 50000
    int E = in_sizes[2] / 2;       // 800000

    // ---- workspace layout (256B-aligned chunks) ----
    char* ws = (char*)d_ws;
    size_t off = 0;
    auto alloc = [&](size_t bytes) { void* p = ws + off; off += (bytes + 255) & ~(size_t)255; return p; };

    uint32_t* flags = (uint32_t*)alloc(256);
    uint16_t* WT    = (uint16_t*)alloc(6 * 65536 * sizeof(uint16_t));          // 768 KB
    const uint32_t POS_OFF = 0;
    const uint32_t W1A_OFF = POS_OFF + (uint32_t)(N * 3);
    const uint32_t W2A_OFF = W1A_OFF + 66304;
    const uint32_t W1B_OFF = W2A_OFF + 66304;
    const uint32_t W2B_OFF = W1B_OFF + 65536;
    const uint32_t WD1_OFF = W2B_OFF + 65536;
    const uint32_t WD2_OFF = WD1_OFF + 65536;
    const uint32_t B1A_OFF = WD2_OFF + 65536;
    const uint32_t B1B_OFF = B1A_OFF + 256;
    const uint32_t B2A_OFF = B1B_OFF + 256;
    const uint32_t B2B_OFF = B2A_OFF + 256;
    const uint32_t BD1_OFF = B2B_OFF + 256;
    const uint32_t BD2_OFF = BD1_OFF + 256;
    const uint32_t ARENA_ELEMS = BD2_OFF + 256;
    uint16_t* arena = (uint16_t*)alloc((size_t)ARENA_ELEMS * 2);
    int*      hist  = (int*)alloc((size_t)N * 4);
    int*      curs  = (int*)alloc((size_t)N * 4);
    int*      part  = (int*)alloc(1024 * 4);
    int*      carry = (int*)alloc(1024 * 4);
    int*      esrc  = (int*)alloc((size_t)E * 4);
    int*      edst  = (int*)alloc((size_t)E * 4);
    uint16_t* Qb    = (uint16_t*)alloc((size_t)N * 256 * 2);                   // 25.6 MB
    uint16_t* Gs    = (uint16_t*)alloc((size_t)N * 256 * 2);                   // 25.6 MB (bf16 now)
    uint32_t* agg   = (uint32_t*)alloc((size_t)N * 256 * 4);                   // 51.2 MB
    uint16_t* xb    = (uint16_t*)alloc((size_t)N * 256 * 2);                   // 25.6 MB
    uint16_t* h     = xb;               // alias: xb dead after layer-1 node GEMM
    uint16_t* d1    = Gs;               // alias: Gs dead after layer-2 edge pass

    uint16_t* posb = arena + POS_OFF;
    uint16_t* w1a = arena + W1A_OFF, * w2a = arena + W2A_OFF;
    uint16_t* w1b = arena + W1B_OFF, * w2b = arena + W2B_OFF;
    uint16_t* wd1 = arena + WD1_OFF, * wd2 = arena + WD2_OFF;
    uint16_t* b1a = arena + B1A_OFF, * b1b = arena + B1B_OFF;
    uint16_t* b2a = arena + B2A_OFF, * b2b = arena + B2B_OFF;
    uint16_t* bd1 = arena + BD1_OFF, * bd2 = arena + BD2_OFF;

    int n4      = N * 64;
    int nbElem  = (n4 + 255) / 256;
    int nbNode  = (N + 63) / 64;
    int nbEdge  = (E + 63) / 64;
    int nbE256  = (E + 255) / 256;
    int nbPos   = (N + 7) / 8;
    int nbScan  = (N + 1023) / 1024;

    // ---- detection + canonicalization ----
    detect_fmt<<<1, 64, 0, stream>>>((const uint32_t*)x_raw, (const uint32_t*)ei_raw, flags);
    convert_big<<<(N * 256 / 4 + 255) / 256, 256, 0, stream>>>(x_raw, xb, N * 256, flags);

    ConvArgs ca;
    ca.src[0] = pos_raw;  ca.dstOff[0] = POS_OFF; ca.n[0] = (uint32_t)(N * 3);
    ca.src[1] = d_in[3];  ca.dstOff[1] = W1A_OFF; ca.n[1] = 66304;
    ca.src[2] = d_in[7];  ca.dstOff[2] = W2A_OFF; ca.n[2] = 66304;
    ca.src[3] = d_in[5];  ca.dstOff[3] = W1B_OFF; ca.n[3] = 65536;
    ca.src[4] = d_in[9];  ca.dstOff[4] = W2B_OFF; ca.n[4] = 65536;
    ca.src[5] = d_in[11]; ca.dstOff[5] = WD1_OFF; ca.n[5] = 65536;
    ca.src[6] = d_in[13]; ca.dstOff[6] = WD2_OFF; ca.n[6] = 65536;
    ca.src[7] = d_in[4];  ca.dstOff[7] = B1A_OFF; ca.n[7] = 256;
    ca.src[8] = d_in[6];  ca.dstOff[8] = B1B_OFF; ca.n[8] = 256;
    ca.src[9] = d_in[8];  ca.dstOff[9] = B2A_OFF; ca.n[9] = 256;
    ca.src[10] = d_in[10]; ca.dstOff[10] = B2B_OFF; ca.n[10] = 256;
    ca.src[11] = d_in[12]; ca.dstOff[11] = BD1_OFF; ca.n[11] = 256;
    ca.src[12] = d_in[14]; ca.dstOff[12] = BD2_OFF; ca.n[12] = 256;
    {
        uint32_t maxn = (uint32_t)(N * 3);
        dim3 g((maxn + 255) / 256, 13);
        convert_small<<<g, 256, 0, stream>>>(ca, arena, flags);
    }

    // ---- counting sort of edges by dst (once, reused by both layers) ----
    zero_i32<<<(N + 255) / 256, 256, 0, stream>>>(hist, N);
    hist_dst<<<nbE256, 256, 0, stream>>>(ei_raw, E, hist, flags);
    scan_partial<<<nbScan, 1024, 0, stream>>>(hist, curs, part, N);
    scan_carry<<<1, 1024, 0, stream>>>(part, carry, nbScan);
    scan_add<<<nbScan, 1024, 0, stream>>>(curs, carry, N);
    scatter_edges<<<nbE256, 256, 0, stream>>>(ei_raw, E, curs, esrc, edst, flags);

    transpose_w<<<dim3(256, 6), 256, 0, stream>>>(w1a, w1b, w2a, w2b, wd1, wd2, WT);

    // ---- layer 1 ----
    pos_proj<<<nbPos, 256, 0, stream>>>(posb, w1a + 65536, Qb, N);
    gemm_node<0><<<nbNode, 256, 0, stream>>>(xb, WT + 0 * 65536, b1a, Qb, Gs, N, flags);
    init_agg<<<nbElem, 256, 0, stream>>>(agg, n4);
    edge_gemm_agg<<<nbEdge, 256, 0, stream>>>(Gs, Qb, WT + 1 * 65536, b1b, esrc, edst, E, agg);
    finalize_init<<<nbElem, 256, 0, stream>>>(agg, h, n4);

    // ---- layer 2 ----
    pos_proj<<<nbPos, 256, 0, stream>>>(posb, w2a + 65536, Qb, N);
    gemm_node<0><<<nbNode, 256, 0, stream>>>(h, WT + 2 * 65536, b2a, Qb, Gs, N, flags);
    edge_gemm_agg<<<nbEdge, 256, 0, stream>>>(Gs, Qb, WT + 3 * 65536, b2b, esrc, edst, E, agg);
    finalize_init<<<nbElem, 256, 0, stream>>>(agg, h, n4);

    // ---- decoder ----
    gemm_node<1><<<nbNode, 256, 0, stream>>>(h, WT + 4 * 65536, bd1, nullptr, d1, N, flags);
    gemm_node<2><<<nbNode, 256, 0, stream>>>(d1, WT + 5 * 65536, bd2, nullptr, d_out, N, flags);
}

// Round 6
// 850.007 us; speedup vs baseline: 1.7645x; 1.7645x over previous
//
#include <hip/hip_runtime.h>
#include <stdint.h>

// ---------------------------------------------------------------------------
// PointNet-style graph autoencoder, MI355X (gfx950).
//
// R6: R4 structure (non-pipelined K-loop; no live-across-barrier prefetch
// registers: with __launch_bounds__(256,4) the budget is exactly VGPR64 +
// AGPR64 and any extra spills to scratch -- R5's 785 MB WRITE_SIZE lesson),
// keeping R5's wins: bf16 Gs (L2-resident gather), parallel 3-kernel scan,
// fused finalize+init.
// Edges counting-sorted by dst once; one atomicMax per (run, col).
// ---------------------------------------------------------------------------

using bf16x8 = __attribute__((ext_vector_type(8))) short;
using f32x4  = __attribute__((ext_vector_type(4))) float;

#define AB_STRIDE 40      // shorts per staged row (32 k + 8 pad) -> 16B aligned
#define ZSTRIDE   68      // shorts per Z column (64 rows + 4 pad)

__device__ __forceinline__ float b2f(uint32_t v16) {          // bf16 bits -> f32
    return __uint_as_float(v16 << 16);
}
__device__ __forceinline__ float b2f_hi(uint32_t w) {         // high bf16 of word
    return __uint_as_float(w & 0xffff0000u);
}
__device__ __forceinline__ uint16_t f2b(float f) {            // f32 -> bf16 (RNE)
    uint32_t u = __float_as_uint(f);
    u += 0x7fffu + ((u >> 16) & 1u);
    return (uint16_t)(u >> 16);
}
#if __has_builtin(__builtin_amdgcn_cvt_pk_bf16_f32)
__device__ __forceinline__ uint32_t pack2bf(float lo, float hi) {
    auto r = __builtin_amdgcn_cvt_pk_bf16_f32(lo, hi);   // RNE
    uint32_t u; __builtin_memcpy(&u, &r, 4); return u;
}
#else
__device__ __forceinline__ uint32_t pack2bf(float lo, float hi) {
    return (uint32_t)f2b(lo) | ((uint32_t)f2b(hi) << 16);
}
#endif
// monotone float<->uint mapping for atomicMax-based segment_max
__device__ __forceinline__ uint32_t encf(float f) {
    uint32_t u = __float_as_uint(f);
    return (u & 0x80000000u) ? ~u : (u | 0x80000000u);
}
__device__ __forceinline__ float decf(uint32_t k) {
    uint32_t u = (k & 0x80000000u) ? (k & 0x7fffffffu) : ~k;
    return __uint_as_float(u);
}

// ---------------------------------------------------------------------------
// Dtype detection. flags[0]=1 if float tensors are fp32 (else bf16),
// flags[1]=1 if edge_index is int64 (else int32).
// ---------------------------------------------------------------------------
__global__ void detect_fmt(const uint32_t* __restrict__ x,
                           const uint32_t* __restrict__ ei,
                           uint32_t* __restrict__ flags) {
    if (threadIdx.x == 0 && blockIdx.x == 0) {
        int plaus = 0;
        for (int i = 0; i < 64; i++) {
            uint32_t v = x[i];
            uint32_t e = (v >> 23) & 0xffu;
            if (v == 0u || (e >= 96u && e <= 150u)) plaus++;
        }
        flags[0] = (plaus >= 48) ? 1u : 0u;
        int zeros = 0;
        for (int i = 0; i < 16; i++)
            if (ei[2 * i + 1] == 0u) zeros++;
        flags[1] = (zeros == 16) ? 1u : 0u;
    }
}

// big float tensor -> canonical bf16 (4 elems/thread)
__global__ __launch_bounds__(256) void convert_big(
        const void* __restrict__ src, uint16_t* __restrict__ dst, int n,
        const uint32_t* __restrict__ flags) {
    bool isf32 = flags[0] != 0u;
    int i = (blockIdx.x * 256 + threadIdx.x) * 4;
    if (i + 3 < n) {
        if (isf32) {
            float4 v = ((const float4*)src)[i >> 2];
            uint2 o = {pack2bf(v.x, v.y), pack2bf(v.z, v.w)};
            ((uint2*)dst)[i >> 2] = o;
        } else {
            ((uint2*)dst)[i >> 2] = ((const uint2*)src)[i >> 2];
        }
    } else {
        for (int j = i; j < n; j++)
            dst[j] = isf32 ? f2b(((const float*)src)[j]) : ((const uint16_t*)src)[j];
    }
}

struct ConvArgs {
    const void* src[13];
    uint32_t dstOff[13];
    uint32_t n[13];
};

// batched small float tensors -> canonical bf16 arena
__global__ __launch_bounds__(256) void convert_small(
        ConvArgs a, uint16_t* __restrict__ dstBase, const uint32_t* __restrict__ flags) {
    bool isf32 = flags[0] != 0u;
    int t = blockIdx.y;
    int i = blockIdx.x * 256 + threadIdx.x;
    if (i >= (int)a.n[t]) return;
    uint16_t* d = dstBase + a.dstOff[t];
    d[i] = isf32 ? f2b(((const float*)a.src[t])[i]) : ((const uint16_t*)a.src[t])[i];
}

// ---------------------------------------------------------------------------
// Counting sort of edges by dst (parallel 3-kernel scan).
// ---------------------------------------------------------------------------
__global__ __launch_bounds__(256) void zero_i32(int* p, int n) {
    int i = blockIdx.x * 256 + threadIdx.x;
    if (i < n) p[i] = 0;
}

__global__ __launch_bounds__(256) void hist_dst(
        const int* __restrict__ ei_raw, int E, int* __restrict__ hist,
        const uint32_t* __restrict__ flags) {
    bool i64 = flags[1] != 0u;
    int e = blockIdx.x * 256 + threadIdx.x;
    if (e < E) {
        int d = i64 ? ei_raw[2 * (E + e)] : ei_raw[E + e];
        atomicAdd(&hist[d], 1);
    }
}

// per-1024-chunk exclusive scan + chunk totals
__global__ __launch_bounds__(1024) void scan_partial(
        const int* __restrict__ hist, int* __restrict__ cursor,
        int* __restrict__ part, int N) {
    __shared__ int wsum[16];
    int tid = threadIdx.x, lane = tid & 63, wid = tid >> 6;
    int base = blockIdx.x * 1024;
    int v = (base + tid < N) ? hist[base + tid] : 0;
    int x = v;
#pragma unroll
    for (int s = 1; s < 64; s <<= 1) {
        int t = __shfl_up(x, s, 64);
        if (lane >= s) x += t;
    }
    if (lane == 63) wsum[wid] = x;
    __syncthreads();
    if (wid == 0 && lane < 16) {
        int w = wsum[lane];
#pragma unroll
        for (int s = 1; s < 16; s <<= 1) {
            int t = __shfl_up(w, s, 64);
            if (lane >= s) w += t;
        }
        wsum[lane] = w;
    }
    __syncthreads();
    int wbase = (wid > 0) ? wsum[wid - 1] : 0;
    if (base + tid < N) cursor[base + tid] = x - v + wbase;
    if (tid == 0) part[blockIdx.x] = wsum[15];
}

// exclusive scan of chunk totals (B <= 1024)
__global__ __launch_bounds__(1024) void scan_carry(
        const int* __restrict__ part, int* __restrict__ carry, int B) {
    __shared__ int wsum[16];
    int tid = threadIdx.x, lane = tid & 63, wid = tid >> 6;
    int v = (tid < B) ? part[tid] : 0;
    int x = v;
#pragma unroll
    for (int s = 1; s < 64; s <<= 1) {
        int t = __shfl_up(x, s, 64);
        if (lane >= s) x += t;
    }
    if (lane == 63) wsum[wid] = x;
    __syncthreads();
    if (wid == 0 && lane < 16) {
        int w = wsum[lane];
#pragma unroll
        for (int s = 1; s < 16; s <<= 1) {
            int t = __shfl_up(w, s, 64);
            if (lane >= s) w += t;
        }
        wsum[lane] = w;
    }
    __syncthreads();
    int wbase = (wid > 0) ? wsum[wid - 1] : 0;
    if (tid < B) carry[tid] = x - v + wbase;
}

__global__ __launch_bounds__(1024) void scan_add(
        int* __restrict__ cursor, const int* __restrict__ carry, int N) {
    int i = blockIdx.x * 1024 + threadIdx.x;
    if (i < N) cursor[i] += carry[blockIdx.x];
}

__global__ __launch_bounds__(256) void scatter_edges(
        const int* __restrict__ ei_raw, int E, int* __restrict__ cursor,
        int* __restrict__ esrc, int* __restrict__ edst,
        const uint32_t* __restrict__ flags) {
    bool i64 = flags[1] != 0u;
    int e = blockIdx.x * 256 + threadIdx.x;
    if (e < E) {
        int s = i64 ? ei_raw[2 * e] : ei_raw[e];
        int d = i64 ? ei_raw[2 * (E + e)] : ei_raw[E + e];
        int p = atomicAdd(&cursor[d], 1);
        esrc[p] = s;
        edst[p] = d;
    }
}

// ---------------------------------------------------------------------------
// Transpose+chunk-tile the 6 [256x256] B-matrices into WT (32-k chunks):
//   WT[w][ (k>>5)*8192 + n*32 + (k&31) ] = W[k*256 + n]
// ---------------------------------------------------------------------------
__global__ __launch_bounds__(256) void transpose_w(
        const uint16_t* s0, const uint16_t* s1, const uint16_t* s2,
        const uint16_t* s3, const uint16_t* s4, const uint16_t* s5,
        uint16_t* dst) {
    const uint16_t* srcs[6] = {s0, s1, s2, s3, s4, s5};
    const uint16_t* src = srcs[blockIdx.y];
    uint16_t* d = dst + (size_t)blockIdx.y * 65536;
    int k = blockIdx.x;          // grid.x = 256
    int n = threadIdx.x;
    d[(k >> 5) * 8192 + n * 32 + (k & 31)] = src[k * 256 + n];
}

// Q[i][c] = sum_d pos[i][d] * wpos[d][c]   (wpos = wA rows 256..258)
__global__ __launch_bounds__(256) void pos_proj(
        const uint16_t* pos, const uint16_t* wpos, uint16_t* Q, int N) {
    int c = threadIdx.x;
    float w0 = b2f(wpos[c]), w1 = b2f(wpos[256 + c]), w2 = b2f(wpos[512 + c]);
    int base = blockIdx.x * 8;
#pragma unroll
    for (int n = 0; n < 8; n++) {
        int i = base + n;
        if (i >= N) break;
        float p0 = b2f(pos[i * 3 + 0]);
        float p1 = b2f(pos[i * 3 + 1]);
        float p2 = b2f(pos[i * 3 + 2]);
        Q[(size_t)i * 256 + c] = f2b(p0 * w0 + p1 * w1 + p2 * w2);
    }
}

__global__ __launch_bounds__(256) void init_agg(uint32_t* agg, int n4) {
    int i = blockIdx.x * 256 + threadIdx.x;
    if (i < n4) {
        uint4 v = {0x80000000u, 0x80000000u, 0x80000000u, 0x80000000u};  // enc(+0)
        ((uint4*)agg)[i] = v;
    }
}

// fused: h = bf16(dec(agg)); agg = enc(0) for the next layer
__global__ __launch_bounds__(256) void finalize_init(
        uint32_t* __restrict__ agg, uint16_t* __restrict__ h, int n4) {
    int i = blockIdx.x * 256 + threadIdx.x;
    if (i < n4) {
        uint4 a = ((uint4*)agg)[i];
        uint2 o = {pack2bf(decf(a.x), decf(a.y)), pack2bf(decf(a.z), decf(a.w))};
        ((uint2*)h)[i] = o;
        uint4 z = {0x80000000u, 0x80000000u, 0x80000000u, 0x80000000u};
        ((uint4*)agg)[i] = z;
    }
}

// ---------------------------------------------------------------------------
// Node GEMM (BK=32, non-pipelined): C[M,256] = A @ W (+bias) (+Q) (...)
// Tile: 64 rows x 256 cols, 256 threads / 4 waves; wave w owns cols [w*64,+64).
// MODE 0: out bf16, +bias +Q (Gs build).  MODE 1: out bf16, +bias, relu.
// MODE 2: out per-flag dtype, +bias (final decoder stage).
// ---------------------------------------------------------------------------
template <int MODE>
__global__ __launch_bounds__(256) void gemm_node(
        const uint16_t* __restrict__ A, const uint16_t* __restrict__ BT,
        const uint16_t* __restrict__ bias, const uint16_t* __restrict__ Qadd,
        void* __restrict__ out, int M, const uint32_t* __restrict__ flags) {
    __shared__ __align__(16) uint16_t Al[64 * AB_STRIDE];
    __shared__ __align__(16) uint16_t Bl[256 * AB_STRIDE];
    int tid = threadIdx.x;
    int tileM = blockIdx.x;
    int wave = tid >> 6, lane = tid & 63, lrow = lane & 15, quad = lane >> 4;
    f32x4 acc[4][4] = {};

    int row = tid >> 2, kq = (tid & 3) * 8;
    for (int kc = 0; kc < 256; kc += 32) {
        {   // stage A chunk: 64 rows x 32 k, 8 shorts / thread
            int rg = tileM * 64 + row;
            uint4 v = {0, 0, 0, 0};
            if (rg < M) v = *(const uint4*)(A + (size_t)rg * 256 + kc + kq);
            *(uint4*)&Al[row * AB_STRIDE + kq] = v;
        }
        {   // stage B chunk: 64 B / thread
            const uint4* p = (const uint4*)(BT + (kc >> 5) * 8192 + tid * 32);
#pragma unroll
            for (int j = 0; j < 4; j++) *(uint4*)&Bl[tid * AB_STRIDE + j * 8] = p[j];
        }
        __syncthreads();
        bf16x8 af[4], bfr[4];
#pragma unroll
        for (int r = 0; r < 4; r++)
            af[r] = *(const bf16x8*)&Al[(r * 16 + lrow) * AB_STRIDE + quad * 8];
#pragma unroll
        for (int c = 0; c < 4; c++)
            bfr[c] = *(const bf16x8*)&Bl[(wave * 64 + c * 16 + lrow) * AB_STRIDE + quad * 8];
#pragma unroll
        for (int r = 0; r < 4; r++)
#pragma unroll
            for (int c = 0; c < 4; c++)
                acc[r][c] = __builtin_amdgcn_mfma_f32_16x16x32_bf16(af[r], bfr[c], acc[r][c], 0, 0, 0);
        __syncthreads();
    }

    bool of32 = false;
    if (MODE == 2) of32 = flags[0] != 0u;

#pragma unroll
    for (int c = 0; c < 4; c++) {
        int col = wave * 64 + c * 16 + lrow;
        float bv = b2f(bias[col]);
#pragma unroll
        for (int r = 0; r < 4; r++) {
#pragma unroll
            for (int i = 0; i < 4; i++) {
                int rw = tileM * 64 + r * 16 + quad * 4 + i;
                if (rw >= M) continue;
                float v = acc[r][c][i] + bv;
                if (MODE == 0) {
                    v += b2f(Qadd[(size_t)rw * 256 + col]);
                    ((uint16_t*)out)[(size_t)rw * 256 + col] = f2b(v);
                } else if (MODE == 1) {
                    v = fmaxf(v, 0.f);
                    ((uint16_t*)out)[(size_t)rw * 256 + col] = f2b(v);
                } else {
                    if (of32) ((float*)out)[(size_t)rw * 256 + col] = v;
                    else      ((uint16_t*)out)[(size_t)rw * 256 + col] = f2b(v);
                }
            }
        }
    }
}

// ---------------------------------------------------------------------------
// Edge kernel over dst-SORTED edges (BK=32, non-pipelined):
// tile = 64 edges x 256 cols. m = relu(Gs16[src] - Q[dst]) -> bf16 (Gs bf16,
// L2-resident); z = m @ wB + bB. Z parked col-major in LDS (overlay);
// run-max scan with ballot mask; one coalesced atomicMax per (run, col).
// ---------------------------------------------------------------------------
__global__ __launch_bounds__(256, 4) void edge_gemm_agg(
        const uint16_t* __restrict__ Gs16, const uint16_t* __restrict__ Qb,
        const uint16_t* __restrict__ BT, const uint16_t* __restrict__ bias,
        const int* __restrict__ esrc, const int* __restrict__ edst, int E,
        uint32_t* __restrict__ agg) {
    __shared__ __align__(16) uint16_t SM[256 * ZSTRIDE];     // 34816 B
    uint16_t* Al = SM;                       // 64 x AB_STRIDE
    uint16_t* Bl = SM + 64 * AB_STRIDE;      // 256 x AB_STRIDE
    uint16_t* Zl = SM;                       // overlay: col-major 256 x ZSTRIDE
    __shared__ int ssrc[64], sdst[64];
    __shared__ uint64_t smask;
    int tid = threadIdx.x;
    int ebase = blockIdx.x * 64;
    int evalid = (E - ebase < 64) ? (E - ebase) : 64;
    if (tid < 64) {
        int s = 0, d = 0;
        if (tid < evalid) {
            s = esrc[ebase + tid];
            d = edst[ebase + tid];
        }
        ssrc[tid] = s;
        sdst[tid] = d;
    }
    __syncthreads();
    int wave = tid >> 6, lane = tid & 63, lrow = lane & 15, quad = lane >> 4;
    f32x4 acc[4][4] = {};

    int row = tid >> 2, kq = (tid & 3) * 8;
    int s = ssrc[row], dd = sdst[row];
    const uint16_t* gbase = Gs16 + (size_t)s * 256 + kq;
    const uint16_t* qbase = Qb + (size_t)dd * 256 + kq;

    for (int kc = 0; kc < 256; kc += 32) {
        {   // stage A: gather bf16 + relu(sub) + pk-bf16 pack, 8 elems / thread
            uint4 ga = *(const uint4*)(gbase + kc);
            uint4 qa = *(const uint4*)(qbase + kc);
            uint32_t gw[4] = {ga.x, ga.y, ga.z, ga.w};
            uint32_t qw[4] = {qa.x, qa.y, qa.z, qa.w};
            uint32_t mw[4];
#pragma unroll
            for (int j = 0; j < 4; j++) {
                float lo = fmaxf(b2f(gw[j] & 0xffffu) - b2f(qw[j] & 0xffffu), 0.f);
                float hi = fmaxf(b2f_hi(gw[j]) - b2f_hi(qw[j]), 0.f);
                mw[j] = pack2bf(lo, hi);
            }
            uint4 wv = {mw[0], mw[1], mw[2], mw[3]};
            *(uint4*)&Al[row * AB_STRIDE + kq] = wv;
        }
        {   // stage B: 64 B / thread, contiguous (WT is L2-hot)
            const uint4* p = (const uint4*)(BT + (kc >> 5) * 8192 + tid * 32);
#pragma unroll
            for (int j = 0; j < 4; j++) *(uint4*)&Bl[tid * AB_STRIDE + j * 8] = p[j];
        }
        __syncthreads();
        bf16x8 af[4], bfr[4];
#pragma unroll
        for (int r = 0; r < 4; r++)
            af[r] = *(const bf16x8*)&Al[(r * 16 + lrow) * AB_STRIDE + quad * 8];
#pragma unroll
        for (int c = 0; c < 4; c++)
            bfr[c] = *(const bf16x8*)&Bl[(wave * 64 + c * 16 + lrow) * AB_STRIDE + quad * 8];
#pragma unroll
        for (int r = 0; r < 4; r++)
#pragma unroll
            for (int c = 0; c < 4; c++)
                acc[r][c] = __builtin_amdgcn_mfma_f32_16x16x32_bf16(af[r], bfr[c], acc[r][c], 0, 0, 0);
        __syncthreads();
    }

    // park z = acc + bias in LDS col-major as bf16 (RNE monotone: commutes w/ max)
    float bv[4];
#pragma unroll
    for (int c = 0; c < 4; c++) bv[c] = b2f(bias[wave * 64 + c * 16 + lrow]);
#pragma unroll
    for (int c = 0; c < 4; c++) {
        int col = wave * 64 + c * 16 + lrow;
#pragma unroll
        for (int r = 0; r < 4; r++) {
            uint2 z4 = {pack2bf(acc[r][c][0] + bv[c], acc[r][c][1] + bv[c]),
                        pack2bf(acc[r][c][2] + bv[c], acc[r][c][3] + bv[c])};
            *(uint2*)&Zl[col * ZSTRIDE + r * 16 + quad * 4] = z4;
        }
    }
    // run-boundary mask (uniform): bit r set where sdst[r] != sdst[r-1]
    if (wave == 0) {
        int d0 = sdst[lane];
        int dp = (lane > 0) ? sdst[lane - 1] : -1;
        uint64_t m = __ballot(d0 != dp);
        if (lane == 0) smask = m;
    }
    __syncthreads();

    // run-max over sorted dst, one coalesced atomic per (run, col)
    uint64_t mask = smask;
    int col = tid;
    const uint16_t* zc = &Zl[col * ZSTRIDE];
    float run = 0.f;
#pragma unroll 4
    for (int g = 0; g < 16; g++) {
        int rbase = g * 4;
        if (rbase >= evalid) break;
        uint2 z4 = *(const uint2*)&zc[rbase];
        float vv[4] = {b2f(z4.x & 0xffffu), b2f_hi(z4.x),
                       b2f(z4.y & 0xffffu), b2f_hi(z4.y)};
#pragma unroll
        for (int i = 0; i < 4; i++) {
            int r = rbase + i;
            if (r >= evalid) break;
            if (r == 0) {
                run = vv[0];
            } else if ((mask >> r) & 1ull) {
                int dp = sdst[r - 1];
                atomicMax(agg + (size_t)dp * 256 + col, encf(run));
                run = vv[i];
            } else {
                run = fmaxf(run, vv[i]);
            }
        }
    }
    if (evalid > 0)
        atomicMax(agg + (size_t)sdst[evalid - 1] * 256 + col, encf(run));
}

// ---------------------------------------------------------------------------
extern "C" void kernel_launch(void* const* d_in, const int* in_sizes, int n_in,
                              void* d_out, int out_size, void* d_ws, size_t ws_size,
                              hipStream_t stream) {
    const void* x_raw   = d_in[0];
    const void* pos_raw = d_in[1];
    const int*  ei_raw  = (const int*)d_in[2];

    int N = in_sizes[0] / 256;     // 50000
    int E = in_sizes[2] / 2;       // 800000

    // ---- workspace layout (256B-aligned chunks) ----
    char* ws = (char*)d_ws;
    size_t off = 0;
    auto alloc = [&](size_t bytes) { void* p = ws + off; off += (bytes + 255) & ~(size_t)255; return p; };

    uint32_t* flags = (uint32_t*)alloc(256);
    uint16_t* WT    = (uint16_t*)alloc(6 * 65536 * sizeof(uint16_t));          // 768 KB
    const uint32_t POS_OFF = 0;
    const uint32_t W1A_OFF = POS_OFF + (uint32_t)(N * 3);
    const uint32_t W2A_OFF = W1A_OFF + 66304;
    const uint32_t W1B_OFF = W2A_OFF + 66304;
    const uint32_t W2B_OFF = W1B_OFF + 65536;
    const uint32_t WD1_OFF = W2B_OFF + 65536;
    const uint32_t WD2_OFF = WD1_OFF + 65536;
    const uint32_t B1A_OFF = WD2_OFF + 65536;
    const uint32_t B1B_OFF = B1A_OFF + 256;
    const uint32_t B2A_OFF = B1B_OFF + 256;
    const uint32_t B2B_OFF = B2A_OFF + 256;
    const uint32_t BD1_OFF = B2B_OFF + 256;
    const uint32_t BD2_OFF = BD1_OFF + 256;
    const uint32_t ARENA_ELEMS = BD2_OFF + 256;
    uint16_t* arena = (uint16_t*)alloc((size_t)ARENA_ELEMS * 2);
    int*      hist  = (int*)alloc((size_t)N * 4);
    int*      curs  = (int*)alloc((size_t)N * 4);
    int*      part  = (int*)alloc(1024 * 4);
    int*      carry = (int*)alloc(1024 * 4);
    int*      esrc  = (int*)alloc((size_t)E * 4);
    int*      edst  = (int*)alloc((size_t)E * 4);
    uint16_t* Qb    = (uint16_t*)alloc((size_t)N * 256 * 2);                   // 25.6 MB
    uint16_t* Gs    = (uint16_t*)alloc((size_t)N * 256 * 2);                   // 25.6 MB (bf16)
    uint32_t* agg   = (uint32_t*)alloc((size_t)N * 256 * 4);                   // 51.2 MB
    uint16_t* xb    = (uint16_t*)alloc((size_t)N * 256 * 2);                   // 25.6 MB
    uint16_t* h     = xb;               // alias: xb dead after layer-1 node GEMM
    uint16_t* d1    = Gs;               // alias: Gs dead after layer-2 edge pass

    uint16_t* posb = arena + POS_OFF;
    uint16_t* w1a = arena + W1A_OFF, * w2a = arena + W2A_OFF;
    uint16_t* w1b = arena + W1B_OFF, * w2b = arena + W2B_OFF;
    uint16_t* wd1 = arena + WD1_OFF, * wd2 = arena + WD2_OFF;
    uint16_t* b1a = arena + B1A_OFF, * b1b = arena + B1B_OFF;
    uint16_t* b2a = arena + B2A_OFF, * b2b = arena + B2B_OFF;
    uint16_t* bd1 = arena + BD1_OFF, * bd2 = arena + BD2_OFF;

    int n4      = N * 64;
    int nbElem  = (n4 + 255) / 256;
    int nbNode  = (N + 63) / 64;
    int nbEdge  = (E + 63) / 64;
    int nbE256  = (E + 255) / 256;
    int nbPos   = (N + 7) / 8;
    int nbScan  = (N + 1023) / 1024;

    // ---- detection + canonicalization ----
    detect_fmt<<<1, 64, 0, stream>>>((const uint32_t*)x_raw, (const uint32_t*)ei_raw, flags);
    convert_big<<<(N * 256 / 4 + 255) / 256, 256, 0, stream>>>(x_raw, xb, N * 256, flags);

    ConvArgs ca;
    ca.src[0] = pos_raw;  ca.dstOff[0] = POS_OFF; ca.n[0] = (uint32_t)(N * 3);
    ca.src[1] = d_in[3];  ca.dstOff[1] = W1A_OFF; ca.n[1] = 66304;
    ca.src[2] = d_in[7];  ca.dstOff[2] = W2A_OFF; ca.n[2] = 66304;
    ca.src[3] = d_in[5];  ca.dstOff[3] = W1B_OFF; ca.n[3] = 65536;
    ca.src[4] = d_in[9];  ca.dstOff[4] = W2B_OFF; ca.n[4] = 65536;
    ca.src[5] = d_in[11]; ca.dstOff[5] = WD1_OFF; ca.n[5] = 65536;
    ca.src[6] = d_in[13]; ca.dstOff[6] = WD2_OFF; ca.n[6] = 65536;
    ca.src[7] = d_in[4];  ca.dstOff[7] = B1A_OFF; ca.n[7] = 256;
    ca.src[8] = d_in[6];  ca.dstOff[8] = B1B_OFF; ca.n[8] = 256;
    ca.src[9] = d_in[8];  ca.dstOff[9] = B2A_OFF; ca.n[9] = 256;
    ca.src[10] = d_in[10]; ca.dstOff[10] = B2B_OFF; ca.n[10] = 256;
    ca.src[11] = d_in[12]; ca.dstOff[11] = BD1_OFF; ca.n[11] = 256;
    ca.src[12] = d_in[14]; ca.dstOff[12] = BD2_OFF; ca.n[12] = 256;
    {
        uint32_t maxn = (uint32_t)(N * 3);
        dim3 g((maxn + 255) / 256, 13);
        convert_small<<<g, 256, 0, stream>>>(ca, arena, flags);
    }

    // ---- counting sort of edges by dst (once, reused by both layers) ----
    zero_i32<<<(N + 255) / 256, 256, 0, stream>>>(hist, N);
    hist_dst<<<nbE256, 256, 0, stream>>>(ei_raw, E, hist, flags);
    scan_partial<<<nbScan, 1024, 0, stream>>>(hist, curs, part, N);
    scan_carry<<<1, 1024, 0, stream>>>(part, carry, nbScan);
    scan_add<<<nbScan, 1024, 0, stream>>>(curs, carry, N);
    scatter_edges<<<nbE256, 256, 0, stream>>>(ei_raw, E, curs, esrc, edst, flags);

    transpose_w<<<dim3(256, 6), 256, 0, stream>>>(w1a, w1b, w2a, w2b, wd1, wd2, WT);

    // ---- layer 1 ----
    pos_proj<<<nbPos, 256, 0, stream>>>(posb, w1a + 65536, Qb, N);
    gemm_node<0><<<nbNode, 256, 0, stream>>>(xb, WT + 0 * 65536, b1a, Qb, Gs, N, flags);
    init_agg<<<nbElem, 256, 0, stream>>>(agg, n4);
    edge_gemm_agg<<<nbEdge, 256, 0, stream>>>(Gs, Qb, WT + 1 * 65536, b1b, esrc, edst, E, agg);
    finalize_init<<<nbElem, 256, 0, stream>>>(agg, h, n4);

    // ---- layer 2 ----
    pos_proj<<<nbPos, 256, 0, stream>>>(posb, w2a + 65536, Qb, N);
    gemm_node<0><<<nbNode, 256, 0, stream>>>(h, WT + 2 * 65536, b2a, Qb, Gs, N, flags);
    edge_gemm_agg<<<nbEdge, 256, 0, stream>>>(Gs, Qb, WT + 3 * 65536, b2b, esrc, edst, E, agg);
    finalize_init<<<nbElem, 256, 0, stream>>>(agg, h, n4);

    // ---- decoder ----
    gemm_node<1><<<nbNode, 256, 0, stream>>>(h, WT + 4 * 65536, bd1, nullptr, d1, N, flags);
    gemm_node<2><<<nbNode, 256, 0, stream>>>(d1, WT + 5 * 65536, bd2, nullptr, d_out, N, flags);
}